// Round 1
// baseline (817.302 us; speedup 1.0000x reference)
//
#include <hip/hip_runtime.h>
#include <hip/hip_bf16.h>
#include <math.h>

#define SEQ    2048
#define HIDDEN 4096
#define NH     32
#define NKV    8
#define HD     128
#define QKV_N  6144   // 4096 q + 1024 k + 1024 v

typedef __attribute__((ext_vector_type(8))) short bf16x8;
typedef __attribute__((ext_vector_type(4))) float f32x4;
typedef unsigned short u16;

__device__ inline void gl_lds16(const void* g, void* lds) {
  __builtin_amdgcn_global_load_lds((const __attribute__((address_space(1))) void*)g,
                                   (__attribute__((address_space(3))) void*)lds, 16, 0, 0);
}

__device__ inline u16 f2bf(float f) {
  __hip_bfloat16 h = __float2bfloat16(f);
  return *(u16*)&h;
}
__device__ inline float bf2f(u16 u) {
  __hip_bfloat16 h = *(__hip_bfloat16*)&u;
  return __bfloat162float(h);
}

// ---------------- fp32 -> bf16 conversion (8 elements / thread) ----------------
__global__ void cvt_f32_bf16(const float* __restrict__ src, u16* __restrict__ dst, int n8) {
  int i = blockIdx.x * blockDim.x + threadIdx.x;
  if (i >= n8) return;
  const float4* s = (const float4*)src + (size_t)i * 2;
  float4 a = s[0], b = s[1];
  float v[8] = {a.x, a.y, a.z, a.w, b.x, b.y, b.z, b.w};
  union { u16 o[8]; uint4 u; } pk;
#pragma unroll
  for (int j = 0; j < 8; j++) pk.o[j] = f2bf(v[j]);
  *(uint4*)(dst + (size_t)i * 8) = pk.u;
}

// ---------------- bf16 GEMM, C = A * B^T  (A: MxK, B: NxK, both row-major) ----------------
// m97-style: 128x128 tile, BK=32, global_load_lds width 16, 4 waves (2x2 of 64x64).
template <int OUTF32>
__global__ __launch_bounds__(256) void gemm_bt(const u16* __restrict__ A,
                                               const u16* __restrict__ B,
                                               void* __restrict__ Cout,
                                               int M, int N, int K) {
  __shared__ __align__(16) u16 As[128 * 32];
  __shared__ __align__(16) u16 Bs[128 * 32];
  const int tid = threadIdx.x;
  const int wave = tid >> 6, lane = tid & 63;
  const int quad = lane >> 4, l16 = lane & 15;
  const int wm = wave >> 1, wn = wave & 1;
  const int m0 = blockIdx.y * 128, n0 = blockIdx.x * 128;

  f32x4 acc[4][4] = {};
  const int lrow = lane >> 2;          // 0..15
  const int kchunk = (lane & 3) * 8;   // element offset within 32-k row

  for (int k0 = 0; k0 < K; k0 += 32) {
    __syncthreads();
#pragma unroll
    for (int i = 0; i < 2; i++) {
      int r = wave * 32 + i * 16 + lrow;
      gl_lds16(A + (size_t)(m0 + r) * K + k0 + kchunk, &As[(wave * 32 + i * 16) * 32]);
      gl_lds16(B + (size_t)(n0 + r) * K + k0 + kchunk, &Bs[(wave * 32 + i * 16) * 32]);
    }
    __syncthreads();
    bf16x8 af[4], bfr[4];
#pragma unroll
    for (int t = 0; t < 4; t++) {
      af[t]  = *(const bf16x8*)&As[(wm * 64 + t * 16 + l16) * 32 + quad * 8];
      bfr[t] = *(const bf16x8*)&Bs[(wn * 64 + t * 16 + l16) * 32 + quad * 8];
    }
#pragma unroll
    for (int mt = 0; mt < 4; mt++)
#pragma unroll
      for (int nt = 0; nt < 4; nt++)
        acc[mt][nt] = __builtin_amdgcn_mfma_f32_16x16x32_bf16(af[mt], bfr[nt], acc[mt][nt], 0, 0, 0);
  }

#pragma unroll
  for (int mt = 0; mt < 4; mt++)
#pragma unroll
    for (int nt = 0; nt < 4; nt++)
#pragma unroll
      for (int r = 0; r < 4; r++) {
        int row = m0 + wm * 64 + mt * 16 + quad * 4 + r;
        int col = n0 + wn * 64 + nt * 16 + l16;
        float v = acc[mt][nt][r];
        if (OUTF32) ((float*)Cout)[(size_t)row * N + col] = v;
        else        ((u16*)Cout)[(size_t)row * N + col] = f2bf(v);
      }
}

// ---------------- RoPE in-place on bf16 qkv buffer (q heads 0..31, k heads 0..7) ------------
__global__ void rope_kernel(u16* __restrict__ qkv, const int* __restrict__ pos_ids) {
  int idx = blockIdx.x * blockDim.x + threadIdx.x;   // SEQ*40*64 threads
  int d = idx & 63;
  int h = (idx >> 6) % 40;
  int s = idx / (64 * 40);
  if (s >= SEQ) return;
  int off = (h < NH) ? h * HD : HIDDEN + (h - NH) * HD;
  u16* base = qkv + (size_t)s * QKV_N + off;
  float inv_freq = powf(10000.0f, -(float)d * (1.0f / 64.0f));
  float ang = (float)pos_ids[s] * inv_freq;
  float sn, cs;
  sincosf(ang, &sn, &cs);
  float x1 = bf2f(base[d]);
  float x2 = bf2f(base[d + 64]);
  base[d]      = f2bf(x1 * cs - x2 * sn);
  base[d + 64] = f2bf(x2 * cs + x1 * sn);
}

// ---------------- flash attention: causal GQA, online softmax --------------------------------
// grid: (SEQ/64, NH); block 256 (4 waves). Wave w owns q rows [qb*64+w*16, +16).
#define KS_STRIDE 160   // 128 + 32 pad: 2-way banks, 16B-aligned rows
#define VT_STRIDE 40    // 32 + 8 pad
#define PS_STRIDE 40    // 32 + 8 pad
__global__ __launch_bounds__(256) void attn_kernel(const u16* __restrict__ qkv,
                                                   u16* __restrict__ attn_out) {
  __shared__ __align__(16) u16 Ks[32 * KS_STRIDE];
  __shared__ __align__(16) u16 Vt[128 * VT_STRIDE];
  __shared__ __align__(16) u16 Ps[4][16 * PS_STRIDE];
  const int qb = blockIdx.x;
  const int h  = blockIdx.y;
  const int kvh = h >> 2;
  const int tid = threadIdx.x;
  const int wave = tid >> 6, lane = tid & 63;
  const int quad = lane >> 4, l16 = lane & 15;
  const int q0 = qb * 64 + wave * 16;

  const float sl_scale = 0.08838834764831845f * 1.4426950408889634f; // D^-0.5 * log2(e)

  bf16x8 qf[4];
#pragma unroll
  for (int dc = 0; dc < 4; dc++)
    qf[dc] = *(const bf16x8*)(qkv + (size_t)(q0 + l16) * QKV_N + h * HD + dc * 32 + quad * 8);

  float m_r[4] = {-INFINITY, -INFINITY, -INFINITY, -INFINITY};
  float l_r[4] = {0.f, 0.f, 0.f, 0.f};
  f32x4 o[8] = {};

  const int ktmax = 2 * qb + 1;
  for (int kt = 0; kt <= ktmax; kt++) {
    __syncthreads();
    { // stage K (row-major, padded) and V (transposed, padded)
      int idx = tid * 16;           // element in 32(keys) x 128(d) tile
      int key = idx >> 7, d0 = idx & 127;
      const u16* kg = qkv + (size_t)(kt * 32 + key) * QKV_N + HIDDEN + kvh * HD + d0;
      uint4 k0v = *(const uint4*)kg;
      uint4 k1v = *((const uint4*)kg + 1);
      *(uint4*)&Ks[key * KS_STRIDE + d0] = k0v;
      *((uint4*)&Ks[key * KS_STRIDE + d0] + 1) = k1v;
      const u16* vg = qkv + (size_t)(kt * 32 + key) * QKV_N + HIDDEN + 1024 + kvh * HD + d0;
      union { uint4 u[2]; u16 e[16]; } vv;
      vv.u[0] = *(const uint4*)vg;
      vv.u[1] = *((const uint4*)vg + 1);
#pragma unroll
      for (int e = 0; e < 16; e++) Vt[(d0 + e) * VT_STRIDE + key] = vv.e[e];
    }
    __syncthreads();

    // S = Q K^T : two 16x16 subtiles over 32 keys
    f32x4 sa[2] = {};
#pragma unroll
    for (int st = 0; st < 2; st++)
#pragma unroll
      for (int dc = 0; dc < 4; dc++)
        sa[st] = __builtin_amdgcn_mfma_f32_16x16x32_bf16(
            qf[dc], *(const bf16x8*)&Ks[(st * 16 + l16) * KS_STRIDE + dc * 32 + quad * 8],
            sa[st], 0, 0, 0);

    float sl[2][4];
    const bool need_mask = (kt * 32 + 31 > q0);
#pragma unroll
    for (int st = 0; st < 2; st++)
#pragma unroll
      for (int r = 0; r < 4; r++) {
        float v = sa[st][r] * sl_scale;
        if (need_mask) {
          int row = q0 + quad * 4 + r;
          int key = kt * 32 + st * 16 + l16;
          if (key > row) v = -1e30f;
        }
        sl[st][r] = v;
      }

    float alpha[4];
#pragma unroll
    for (int r = 0; r < 4; r++) {
      float mx = fmaxf(sl[0][r], sl[1][r]);
#pragma unroll
      for (int off = 1; off < 16; off <<= 1) mx = fmaxf(mx, __shfl_xor(mx, off));
      float mnew = fmaxf(m_r[r], mx);
      alpha[r] = exp2f(m_r[r] - mnew);
      float p0 = exp2f(sl[0][r] - mnew);
      float p1 = exp2f(sl[1][r] - mnew);
      sl[0][r] = p0; sl[1][r] = p1;
      float s_ = p0 + p1;
#pragma unroll
      for (int off = 1; off < 16; off <<= 1) s_ += __shfl_xor(s_, off);
      l_r[r] = l_r[r] * alpha[r] + s_;
      m_r[r] = mnew;
    }

    // P: C-layout (row=quad*4+r, col=st*16+l16) -> LDS -> A-frag layout
#pragma unroll
    for (int st = 0; st < 2; st++)
#pragma unroll
      for (int r = 0; r < 4; r++)
        Ps[wave][(quad * 4 + r) * PS_STRIDE + st * 16 + l16] = f2bf(sl[st][r]);
    bf16x8 pf = *(const bf16x8*)&Ps[wave][l16 * PS_STRIDE + quad * 8];

#pragma unroll
    for (int dt = 0; dt < 8; dt++) {
#pragma unroll
      for (int r = 0; r < 4; r++) o[dt][r] *= alpha[r];
      o[dt] = __builtin_amdgcn_mfma_f32_16x16x32_bf16(
          pf, *(const bf16x8*)&Vt[(dt * 16 + l16) * VT_STRIDE + quad * 8], o[dt], 0, 0, 0);
    }
  }

#pragma unroll
  for (int dt = 0; dt < 8; dt++)
#pragma unroll
    for (int r = 0; r < 4; r++) {
      int row = q0 + quad * 4 + r;
      attn_out[(size_t)row * HIDDEN + h * HD + dt * 16 + l16] = f2bf(o[dt][r] / l_r[r]);
    }
}

// ---------------- launch ----------------
extern "C" void kernel_launch(void* const* d_in, const int* in_sizes, int n_in,
                              void* d_out, int out_size, void* d_ws, size_t ws_size,
                              hipStream_t stream) {
  const float* x  = (const float*)d_in[0];
  const int* pos  = (const int*)d_in[1];
  const float* Wq = (const float*)d_in[3];
  const float* Wk = (const float*)d_in[4];
  const float* Wv = (const float*)d_in[5];
  const float* Wo = (const float*)d_in[6];
  float* out = (float*)d_out;

  u16* x_bf    = (u16*)d_ws;                                  // 2048*4096
  u16* Wqkv_bf = x_bf + (size_t)SEQ * HIDDEN;                 // 6144*4096
  u16* qkv_bf  = Wqkv_bf + (size_t)QKV_N * HIDDEN;            // 2048*6144
  u16* attn_bf = qkv_bf + (size_t)SEQ * QKV_N;                // 2048*4096
  u16* Wo_bf   = attn_bf + (size_t)SEQ * HIDDEN;              // 4096*4096

  auto cvt = [&](const float* s, u16* d, size_t n) {
    int n8 = (int)(n / 8);
    cvt_f32_bf16<<<(n8 + 255) / 256, 256, 0, stream>>>(s, d, n8);
  };
  cvt(x,  x_bf,    (size_t)SEQ * HIDDEN);
  cvt(Wq, Wqkv_bf,                         (size_t)4096 * 4096);
  cvt(Wk, Wqkv_bf + (size_t)4096 * 4096,   (size_t)1024 * 4096);
  cvt(Wv, Wqkv_bf + (size_t)5120 * 4096,   (size_t)1024 * 4096);
  cvt(Wo, Wo_bf,   (size_t)4096 * 4096);

  dim3 g1(QKV_N / 128, SEQ / 128);
  gemm_bt<0><<<g1, 256, 0, stream>>>(x_bf, Wqkv_bf, qkv_bf, SEQ, QKV_N, HIDDEN);

  int rope_threads = SEQ * 40 * 64;
  rope_kernel<<<rope_threads / 256, 256, 0, stream>>>(qkv_bf, pos);

  dim3 g2(SEQ / 64, NH);
  attn_kernel<<<g2, 256, 0, stream>>>(qkv_bf, attn_bf);

  dim3 g3(HIDDEN / 128, SEQ / 128);
  gemm_bt<1><<<g3, 256, 0, stream>>>(attn_bf, Wo_bf, out, SEQ, HIDDEN, HIDDEN);
}

// Round 2
// 661.614 us; speedup vs baseline: 1.2353x; 1.2353x over previous
//
#include <hip/hip_runtime.h>
#include <hip/hip_bf16.h>
#include <math.h>

#define SEQ    2048
#define HIDDEN 4096
#define NH     32
#define NKV    8
#define HD     128
#define QKV_N  6144   // 4096 q + 1024 k + 1024 v

typedef __attribute__((ext_vector_type(8))) short bf16x8;
typedef __attribute__((ext_vector_type(4))) float f32x4;
typedef unsigned short u16;

__device__ inline void gl_lds16(const void* g, void* lds) {
  __builtin_amdgcn_global_load_lds((const __attribute__((address_space(1))) void*)g,
                                   (__attribute__((address_space(3))) void*)lds, 16, 0, 0);
}

__device__ inline u16 f2bf(float f) {
  __hip_bfloat16 h = __float2bfloat16(f);
  return *(u16*)&h;
}
__device__ inline float bf2f(u16 u) {
  __hip_bfloat16 h = *(__hip_bfloat16*)&u;
  return __bfloat162float(h);
}

// ---------------- fp32 -> bf16 conversion (8 elements / thread) ----------------
__global__ void cvt_f32_bf16(const float* __restrict__ src, u16* __restrict__ dst, int n8) {
  int i = blockIdx.x * blockDim.x + threadIdx.x;
  if (i >= n8) return;
  const float4* s = (const float4*)src + (size_t)i * 2;
  float4 a = s[0], b = s[1];
  float v[8] = {a.x, a.y, a.z, a.w, b.x, b.y, b.z, b.w};
  union { u16 o[8]; uint4 u; } pk;
#pragma unroll
  for (int j = 0; j < 8; j++) pk.o[j] = f2bf(v[j]);
  *(uint4*)(dst + (size_t)i * 8) = pk.u;
}

// ---------------- bf16 GEMM, C = A * B^T  (A: MxK, B: NxK, both row-major) ----------------
template <int OUTF32>
__global__ __launch_bounds__(256) void gemm_bt(const u16* __restrict__ A,
                                               const u16* __restrict__ B,
                                               void* __restrict__ Cout,
                                               int M, int N, int K) {
  __shared__ __align__(16) u16 As[128 * 32];
  __shared__ __align__(16) u16 Bs[128 * 32];
  const int tid = threadIdx.x;
  const int wave = tid >> 6, lane = tid & 63;
  const int quad = lane >> 4, l16 = lane & 15;
  const int wm = wave >> 1, wn = wave & 1;
  const int m0 = blockIdx.y * 128, n0 = blockIdx.x * 128;

  f32x4 acc[4][4] = {};
  const int lrow = lane >> 2;
  const int kchunk = (lane & 3) * 8;

  for (int k0 = 0; k0 < K; k0 += 32) {
    __syncthreads();
#pragma unroll
    for (int i = 0; i < 2; i++) {
      int r = wave * 32 + i * 16 + lrow;
      gl_lds16(A + (size_t)(m0 + r) * K + k0 + kchunk, &As[(wave * 32 + i * 16) * 32]);
      gl_lds16(B + (size_t)(n0 + r) * K + k0 + kchunk, &Bs[(wave * 32 + i * 16) * 32]);
    }
    __syncthreads();
    bf16x8 af[4], bfr[4];
#pragma unroll
    for (int t = 0; t < 4; t++) {
      af[t]  = *(const bf16x8*)&As[(wm * 64 + t * 16 + l16) * 32 + quad * 8];
      bfr[t] = *(const bf16x8*)&Bs[(wn * 64 + t * 16 + l16) * 32 + quad * 8];
    }
#pragma unroll
    for (int mt = 0; mt < 4; mt++)
#pragma unroll
      for (int nt = 0; nt < 4; nt++)
        acc[mt][nt] = __builtin_amdgcn_mfma_f32_16x16x32_bf16(af[mt], bfr[nt], acc[mt][nt], 0, 0, 0);
  }

#pragma unroll
  for (int mt = 0; mt < 4; mt++)
#pragma unroll
    for (int nt = 0; nt < 4; nt++)
#pragma unroll
      for (int r = 0; r < 4; r++) {
        int row = m0 + wm * 64 + mt * 16 + quad * 4 + r;
        int col = n0 + wn * 64 + nt * 16 + l16;
        float v = acc[mt][nt][r];
        if (OUTF32) ((float*)Cout)[(size_t)row * N + col] = v;
        else        ((u16*)Cout)[(size_t)row * N + col] = f2bf(v);
      }
}

// ---------------- RoPE in-place on bf16 qkv buffer (q heads 0..31, k heads 0..7) ------------
__global__ void rope_kernel(u16* __restrict__ qkv, const int* __restrict__ pos_ids) {
  int idx = blockIdx.x * blockDim.x + threadIdx.x;
  int d = idx & 63;
  int h = (idx >> 6) % 40;
  int s = idx / (64 * 40);
  if (s >= SEQ) return;
  int off = (h < NH) ? h * HD : HIDDEN + (h - NH) * HD;
  u16* base = qkv + (size_t)s * QKV_N + off;
  float inv_freq = powf(10000.0f, -(float)d * (1.0f / 64.0f));
  float ang = (float)pos_ids[s] * inv_freq;
  float sn, cs;
  sincosf(ang, &sn, &cs);
  float x1 = bf2f(base[d]);
  float x2 = bf2f(base[d + 64]);
  base[d]      = f2bf(x1 * cs - x2 * sn);
  base[d + 64] = f2bf(x2 * cs + x1 * sn);
}

// ---------------- V transpose: qkv v-slice [s][c] -> vt[c][s]  (c = kvh*128+d, 1024 x 2048) --
__global__ __launch_bounds__(256) void transpose_v(const u16* __restrict__ qkv,
                                                   u16* __restrict__ vt) {
  __shared__ u16 t[64][72];
  const int s0 = blockIdx.x * 64, c0 = blockIdx.y * 64;
  const int tid = threadIdx.x;
#pragma unroll
  for (int i = 0; i < 2; i++) {
    int r = (tid >> 3) + i * 32;
    int c = (tid & 7) * 8;
    *(uint4*)&t[r][c] = *(const uint4*)&qkv[(size_t)(s0 + r) * QKV_N + 5120 + c0 + c];
  }
  __syncthreads();
#pragma unroll
  for (int i = 0; i < 2; i++) {
    int c = (tid >> 3) + i * 32;
    int s = (tid & 7) * 8;
    union { uint4 u; u16 e[8]; } o;
#pragma unroll
    for (int j = 0; j < 8; j++) o.e[j] = t[s + j][c];
    *(uint4*)&vt[(size_t)(c0 + c) * SEQ + s0 + s] = o.u;
  }
}

// ---------------- flash attention v2: barrier-free, direct-L2 K/V, 32q/wave, 64-key tiles ----
// Each wave owns 32 q rows of one head. No __syncthreads anywhere.
// grid: 512 blocks x 256 threads. Block b -> (qg, h); wave w -> q-tile qg*4+w.
#define PS_STRIDE 72   // 144 B rows: 16B-aligned, conflict-light
__global__ __launch_bounds__(256, 2) void attn_kernel(const u16* __restrict__ qkv,
                                                      const u16* __restrict__ vt,
                                                      u16* __restrict__ attn_out) {
  __shared__ __align__(16) u16 Ps[4][32 * PS_STRIDE];
  const int blk = blockIdx.x;
  // pair blocks so co-resident pairs (b, b+256) have constant total work
  const int qg = (blk < 256) ? (blk >> 5) : (15 - ((blk - 256) >> 5));
  const int h  = blk & 31;
  const int kvh = h >> 2;
  const int tid = threadIdx.x;
  const int wave = tid >> 6, lane = tid & 63;
  const int quad = lane >> 4, l16 = lane & 15;
  const int q0 = qg * 128 + wave * 32;

  const float sl_scale = 0.08838834764831845f * 1.4426950408889634f; // D^-0.5 * log2e

  // Q fragments: A-layout, 2 m-tiles x 4 d-chunks
  bf16x8 qf[2][4];
#pragma unroll
  for (int m = 0; m < 2; m++)
#pragma unroll
    for (int dc = 0; dc < 4; dc++)
      qf[m][dc] = *(const bf16x8*)(qkv + (size_t)(q0 + m * 16 + l16) * QKV_N + h * HD + dc * 32 + quad * 8);

  // K row pointers (per st subtile): row = kt*64 + st*16 + l16, contiguous d at quad*8 (+dc*32 imm)
  const u16* kp[4];
#pragma unroll
  for (int st = 0; st < 4; st++)
    kp[st] = qkv + (size_t)(st * 16 + l16) * QKV_N + HIDDEN + kvh * HD + quad * 8;
  // V^T row pointers (per dt subtile): row = kvh*128 + dt*16 + l16, contiguous keys at quad*8 (+kc*32 imm)
  const u16* vp[8];
#pragma unroll
  for (int dt = 0; dt < 8; dt++)
    vp[dt] = vt + (size_t)(kvh * HD + dt * 16 + l16) * SEQ + quad * 8;

  float m_r[2][4], l_r[2][4];
#pragma unroll
  for (int m = 0; m < 2; m++)
#pragma unroll
    for (int r = 0; r < 4; r++) { m_r[m][r] = -INFINITY; l_r[m][r] = 0.f; }
  f32x4 o[2][8] = {};

  const int n_kt = (q0 + 95) >> 6;   // keys needed: 0 .. q0+31
  for (int kt = 0; kt < n_kt; kt++) {
    const bool last = (kt == n_kt - 1);

    // ---- S = Q K^T over 64 keys (4 st subtiles) ----
    f32x4 s[2][4] = {};
#pragma unroll
    for (int st = 0; st < 4; st++) {
      bf16x8 kst[4];
#pragma unroll
      for (int dc = 0; dc < 4; dc++) kst[dc] = *(const bf16x8*)(kp[st] + dc * 32);
#pragma unroll
      for (int dc = 0; dc < 4; dc++)
#pragma unroll
        for (int m = 0; m < 2; m++)
          s[m][st] = __builtin_amdgcn_mfma_f32_16x16x32_bf16(qf[m][dc], kst[dc], s[m][st], 0, 0, 0);
    }

    // ---- online softmax (per-row over 64 keys: reg-combine over st + 4 shuffles over l16) ----
    float alpha[2][4];
#pragma unroll
    for (int m = 0; m < 2; m++)
#pragma unroll
      for (int r = 0; r < 4; r++) {
#pragma unroll
        for (int st = 0; st < 4; st++) {
          float v = s[m][st][r] * sl_scale;
          if (last) {
            int key = kt * 64 + st * 16 + l16;
            int row = q0 + m * 16 + quad * 4 + r;
            if (key > row) v = -1e30f;
          }
          s[m][st][r] = v;
        }
        float mx = fmaxf(fmaxf(s[m][0][r], s[m][1][r]), fmaxf(s[m][2][r], s[m][3][r]));
#pragma unroll
        for (int off = 1; off < 16; off <<= 1) mx = fmaxf(mx, __shfl_xor(mx, off));
        float mnew = fmaxf(m_r[m][r], mx);
        float a = exp2f(m_r[m][r] - mnew);
        alpha[m][r] = a;
        float sum = 0.f;
#pragma unroll
        for (int st = 0; st < 4; st++) {
          float p = exp2f(s[m][st][r] - mnew);
          s[m][st][r] = p;
          sum += p;
        }
#pragma unroll
        for (int off = 1; off < 16; off <<= 1) sum += __shfl_xor(sum, off);
        l_r[m][r] = l_r[m][r] * a + sum;
        m_r[m][r] = mnew;
        // spill P row to LDS (C-layout -> A-layout transform)
#pragma unroll
        for (int st = 0; st < 4; st++)
          Ps[wave][(m * 16 + quad * 4 + r) * PS_STRIDE + st * 16 + l16] = f2bf(s[m][st][r]);
      }

    // ---- P A-fragments ----
    bf16x8 pf[2][2];
#pragma unroll
    for (int m = 0; m < 2; m++)
#pragma unroll
      for (int kc = 0; kc < 2; kc++)
        pf[m][kc] = *(const bf16x8*)&Ps[wave][(m * 16 + l16) * PS_STRIDE + kc * 32 + quad * 8];

    // ---- O = O*alpha + P V ----
#pragma unroll
    for (int dt = 0; dt < 8; dt++) {
      bf16x8 vf0 = *(const bf16x8*)(vp[dt]);
      bf16x8 vf1 = *(const bf16x8*)(vp[dt] + 32);
#pragma unroll
      for (int m = 0; m < 2; m++) {
#pragma unroll
        for (int r = 0; r < 4; r++) o[m][dt][r] *= alpha[m][r];
        o[m][dt] = __builtin_amdgcn_mfma_f32_16x16x32_bf16(pf[m][0], vf0, o[m][dt], 0, 0, 0);
        o[m][dt] = __builtin_amdgcn_mfma_f32_16x16x32_bf16(pf[m][1], vf1, o[m][dt], 0, 0, 0);
      }
    }

#pragma unroll
    for (int st = 0; st < 4; st++) kp[st] += (size_t)64 * QKV_N;
#pragma unroll
    for (int dt = 0; dt < 8; dt++) vp[dt] += 64;
  }

  // ---- epilogue ----
#pragma unroll
  for (int m = 0; m < 2; m++)
#pragma unroll
    for (int dt = 0; dt < 8; dt++)
#pragma unroll
      for (int r = 0; r < 4; r++) {
        int row = q0 + m * 16 + quad * 4 + r;
        attn_out[(size_t)row * HIDDEN + h * HD + dt * 16 + l16] = f2bf(o[m][dt][r] / l_r[m][r]);
      }
}

// ---------------- launch ----------------
extern "C" void kernel_launch(void* const* d_in, const int* in_sizes, int n_in,
                              void* d_out, int out_size, void* d_ws, size_t ws_size,
                              hipStream_t stream) {
  const float* x  = (const float*)d_in[0];
  const int* pos  = (const int*)d_in[1];
  const float* Wq = (const float*)d_in[3];
  const float* Wk = (const float*)d_in[4];
  const float* Wv = (const float*)d_in[5];
  const float* Wo = (const float*)d_in[6];
  float* out = (float*)d_out;

  u16* x_bf    = (u16*)d_ws;                                  // 2048*4096
  u16* Wqkv_bf = x_bf + (size_t)SEQ * HIDDEN;                 // 6144*4096
  u16* qkv_bf  = Wqkv_bf + (size_t)QKV_N * HIDDEN;            // 2048*6144
  u16* attn_bf = qkv_bf + (size_t)SEQ * QKV_N;                // 2048*4096
  u16* Wo_bf   = attn_bf + (size_t)SEQ * HIDDEN;              // 4096*4096
  u16* vt_bf   = x_bf;   // reuse x_bf region (dead after gemm1); 1024*2048 fits

  auto cvt = [&](const float* s, u16* d, size_t n) {
    int n8 = (int)(n / 8);
    cvt_f32_bf16<<<(n8 + 255) / 256, 256, 0, stream>>>(s, d, n8);
  };
  cvt(x,  x_bf,    (size_t)SEQ * HIDDEN);
  cvt(Wq, Wqkv_bf,                         (size_t)4096 * 4096);
  cvt(Wk, Wqkv_bf + (size_t)4096 * 4096,   (size_t)1024 * 4096);
  cvt(Wv, Wqkv_bf + (size_t)5120 * 4096,   (size_t)1024 * 4096);
  cvt(Wo, Wo_bf,   (size_t)4096 * 4096);

  dim3 g1(QKV_N / 128, SEQ / 128);
  gemm_bt<0><<<g1, 256, 0, stream>>>(x_bf, Wqkv_bf, qkv_bf, SEQ, QKV_N, HIDDEN);

  int rope_threads = SEQ * 40 * 64;
  rope_kernel<<<rope_threads / 256, 256, 0, stream>>>(qkv_bf, pos);

  dim3 gt(SEQ / 64, 1024 / 64);
  transpose_v<<<gt, 256, 0, stream>>>(qkv_bf, vt_bf);

  attn_kernel<<<512, 256, 0, stream>>>(qkv_bf, vt_bf, attn_bf);

  dim3 g3(HIDDEN / 128, SEQ / 128);
  gemm_bt<1><<<g3, 256, 0, stream>>>(attn_bf, Wo_bf, out, SEQ, HIDDEN, HIDDEN);
}

// Round 3
// 639.931 us; speedup vs baseline: 1.2772x; 1.0339x over previous
//
#include <hip/hip_runtime.h>
#include <hip/hip_bf16.h>
#include <math.h>

#define SEQ    2048
#define HIDDEN 4096
#define NH     32
#define NKV    8
#define HD     128
#define QKV_N  6144   // 4096 q + 1024 k + 1024 v

typedef __attribute__((ext_vector_type(8))) short bf16x8;
typedef __attribute__((ext_vector_type(4))) float f32x4;
typedef unsigned short u16;

__device__ inline void gl_lds16(const void* g, void* lds) {
  __builtin_amdgcn_global_load_lds((const __attribute__((address_space(1))) void*)g,
                                   (__attribute__((address_space(3))) void*)lds, 16, 0, 0);
}

__device__ inline u16 f2bf(float f) {
  __hip_bfloat16 h = __float2bfloat16(f);
  return *(u16*)&h;
}
__device__ inline float bf2f(u16 u) {
  __hip_bfloat16 h = *(__hip_bfloat16*)&u;
  return __bfloat162float(h);
}

// ---------------- fp32 -> bf16 conversion (8 elements / thread) ----------------
__global__ void cvt_f32_bf16(const float* __restrict__ src, u16* __restrict__ dst, int n8) {
  int i = blockIdx.x * blockDim.x + threadIdx.x;
  if (i >= n8) return;
  const float4* s = (const float4*)src + (size_t)i * 2;
  float4 a = s[0], b = s[1];
  float v[8] = {a.x, a.y, a.z, a.w, b.x, b.y, b.z, b.w};
  union { u16 o[8]; uint4 u; } pk;
#pragma unroll
  for (int j = 0; j < 8; j++) pk.o[j] = f2bf(v[j]);
  *(uint4*)(dst + (size_t)i * 8) = pk.u;
}

// ---------------- bf16 GEMM, C = A * B^T  (A: MxK, B: NxK, both row-major) ----------------
template <int OUTF32>
__global__ __launch_bounds__(256) void gemm_bt(const u16* __restrict__ A,
                                               const u16* __restrict__ B,
                                               void* __restrict__ Cout,
                                               int M, int N, int K) {
  __shared__ __align__(16) u16 As[128 * 32];
  __shared__ __align__(16) u16 Bs[128 * 32];
  const int tid = threadIdx.x;
  const int wave = tid >> 6, lane = tid & 63;
  const int quad = lane >> 4, l16 = lane & 15;
  const int wm = wave >> 1, wn = wave & 1;
  const int m0 = blockIdx.y * 128, n0 = blockIdx.x * 128;

  f32x4 acc[4][4] = {};
  const int lrow = lane >> 2;
  const int kchunk = (lane & 3) * 8;

  for (int k0 = 0; k0 < K; k0 += 32) {
    __syncthreads();
#pragma unroll
    for (int i = 0; i < 2; i++) {
      int r = wave * 32 + i * 16 + lrow;
      gl_lds16(A + (size_t)(m0 + r) * K + k0 + kchunk, &As[(wave * 32 + i * 16) * 32]);
      gl_lds16(B + (size_t)(n0 + r) * K + k0 + kchunk, &Bs[(wave * 32 + i * 16) * 32]);
    }
    __syncthreads();
    bf16x8 af[4], bfr[4];
#pragma unroll
    for (int t = 0; t < 4; t++) {
      af[t]  = *(const bf16x8*)&As[(wm * 64 + t * 16 + l16) * 32 + quad * 8];
      bfr[t] = *(const bf16x8*)&Bs[(wn * 64 + t * 16 + l16) * 32 + quad * 8];
    }
#pragma unroll
    for (int mt = 0; mt < 4; mt++)
#pragma unroll
      for (int nt = 0; nt < 4; nt++)
        acc[mt][nt] = __builtin_amdgcn_mfma_f32_16x16x32_bf16(af[mt], bfr[nt], acc[mt][nt], 0, 0, 0);
  }

#pragma unroll
  for (int mt = 0; mt < 4; mt++)
#pragma unroll
    for (int nt = 0; nt < 4; nt++)
#pragma unroll
      for (int r = 0; r < 4; r++) {
        int row = m0 + wm * 64 + mt * 16 + quad * 4 + r;
        int col = n0 + wn * 64 + nt * 16 + l16;
        float v = acc[mt][nt][r];
        if (OUTF32) ((float*)Cout)[(size_t)row * N + col] = v;
        else        ((u16*)Cout)[(size_t)row * N + col] = f2bf(v);
      }
}

// ---------------- RoPE in-place on bf16 qkv buffer (q heads 0..31, k heads 0..7) ------------
__global__ void rope_kernel(u16* __restrict__ qkv, const int* __restrict__ pos_ids) {
  int idx = blockIdx.x * blockDim.x + threadIdx.x;
  int d = idx & 63;
  int h = (idx >> 6) % 40;
  int s = idx / (64 * 40);
  if (s >= SEQ) return;
  int off = (h < NH) ? h * HD : HIDDEN + (h - NH) * HD;
  u16* base = qkv + (size_t)s * QKV_N + off;
  float inv_freq = powf(10000.0f, -(float)d * (1.0f / 64.0f));
  float ang = (float)pos_ids[s] * inv_freq;
  float sn, cs;
  sincosf(ang, &sn, &cs);
  float x1 = bf2f(base[d]);
  float x2 = bf2f(base[d + 64]);
  base[d]      = f2bf(x1 * cs - x2 * sn);
  base[d + 64] = f2bf(x2 * cs + x1 * sn);
}

// ---------------- V transpose: qkv v-slice [s][c] -> vt[c][s]  (c = kvh*128+d, 1024 x 2048) --
__global__ __launch_bounds__(256) void transpose_v(const u16* __restrict__ qkv,
                                                   u16* __restrict__ vt) {
  __shared__ u16 t[64][72];
  const int s0 = blockIdx.x * 64, c0 = blockIdx.y * 64;
  const int tid = threadIdx.x;
#pragma unroll
  for (int i = 0; i < 2; i++) {
    int r = (tid >> 3) + i * 32;
    int c = (tid & 7) * 8;
    *(uint4*)&t[r][c] = *(const uint4*)&qkv[(size_t)(s0 + r) * QKV_N + 5120 + c0 + c];
  }
  __syncthreads();
#pragma unroll
  for (int i = 0; i < 2; i++) {
    int c = (tid >> 3) + i * 32;
    int s = (tid & 7) * 8;
    union { uint4 u; u16 e[8]; } o;
#pragma unroll
    for (int j = 0; j < 8; j++) o.e[j] = t[s + j][c];
    *(uint4*)&vt[(size_t)(c0 + c) * SEQ + s0 + s] = o.u;
  }
}

// ---------------- flash attention v3: fixed-M softmax (no in-loop shuffles), split-K ---------
// Block = 128 threads = 2 waves, both on the same (q-tile of 32 rows, head).
// Wave 0 handles even key-tiles (64 keys each), wave 1 odd. With a FIXED softmax
// shift M=32 (exp2(s*c-32)), partials combine by pure addition at the end via LDS.
// Grid = 2048 blocks, longest q-tiles dispatched first for backfill balance.
#define PS_STRIDE 72   // u16 units; 144B rows
#define EX_STRIDE 132  // f32 units; [row][0..127]=o partial, [row][128]=l partial
__global__ __launch_bounds__(128, 3) void attn_kernel(const u16* __restrict__ qkv,
                                                      const u16* __restrict__ vt,
                                                      u16* __restrict__ attn_out) {
  __shared__ __align__(16) u16 Ps[2][32 * PS_STRIDE];
  __shared__ __align__(16) float Ex[32 * EX_STRIDE];
  const int blk = blockIdx.x;
  const int it = 63 - (blk >> 5);      // q-tile index, longest-first
  const int h  = blk & 31;
  const int kvh = h >> 2;
  const int tid = threadIdx.x;
  const int wave = tid >> 6, lane = tid & 63;
  const int quad = lane >> 4, l16 = lane & 15;
  const int q0 = it * 32;

  const float c = 0.08838834764831845f * 1.4426950408889634f; // D^-0.5 * log2e

  // Q fragments: A-layout, 2 m-tiles x 4 d-chunks (both waves load the same Q)
  bf16x8 qf[2][4];
#pragma unroll
  for (int m = 0; m < 2; m++)
#pragma unroll
    for (int dc = 0; dc < 4; dc++)
      qf[m][dc] = *(const bf16x8*)(qkv + (size_t)(q0 + m * 16 + l16) * QKV_N + h * HD + dc * 32 + quad * 8);

  // K row pointers per st subtile; start at this wave's first tile
  const u16* kp[4];
#pragma unroll
  for (int st = 0; st < 4; st++)
    kp[st] = qkv + (size_t)(wave * 64 + st * 16 + l16) * QKV_N + HIDDEN + kvh * HD + quad * 8;
  // V^T row pointers per dt subtile
  const u16* vp[8];
#pragma unroll
  for (int dt = 0; dt < 8; dt++)
    vp[dt] = vt + (size_t)(kvh * HD + dt * 16 + l16) * SEQ + wave * 64 + quad * 8;

  float lsum[2][4] = {};
  f32x4 o[2][8] = {};

  const int n_kt = (q0 + 95) >> 6;   // key tiles covering 0 .. q0+31
  for (int kt = wave; kt < n_kt; kt += 2) {
    const bool last = (kt == n_kt - 1);

    // ---- S = Q K^T over 64 keys ----
    f32x4 s[2][4] = {};
#pragma unroll
    for (int st = 0; st < 4; st++) {
      bf16x8 kst[4];
#pragma unroll
      for (int dc = 0; dc < 4; dc++) kst[dc] = *(const bf16x8*)(kp[st] + dc * 32);
#pragma unroll
      for (int dc = 0; dc < 4; dc++)
#pragma unroll
        for (int m = 0; m < 2; m++)
          s[m][st] = __builtin_amdgcn_mfma_f32_16x16x32_bf16(qf[m][dc], kst[dc], s[m][st], 0, 0, 0);
    }

    // ---- fixed-shift softmax: p = exp2(s*c - 32); accumulate l per-lane ----
#pragma unroll
    for (int m = 0; m < 2; m++)
#pragma unroll
      for (int r = 0; r < 4; r++) {
#pragma unroll
        for (int st = 0; st < 4; st++) {
          float v = fmaf(s[m][st][r], c, -32.0f);
          if (last) {
            int key = kt * 64 + st * 16 + l16;
            int row = q0 + m * 16 + quad * 4 + r;
            if (key > row) v = -1e30f;
          }
          float p = exp2f(v);
          s[m][st][r] = p;
          lsum[m][r] += p;
          Ps[wave][(m * 16 + quad * 4 + r) * PS_STRIDE + st * 16 + l16] = f2bf(p);
        }
      }

    // ---- P A-fragments ----
    bf16x8 pf[2][2];
#pragma unroll
    for (int m = 0; m < 2; m++)
#pragma unroll
      for (int kc = 0; kc < 2; kc++)
        pf[m][kc] = *(const bf16x8*)&Ps[wave][(m * 16 + l16) * PS_STRIDE + kc * 32 + quad * 8];

    // ---- O += P V (no rescale needed) ----
#pragma unroll
    for (int dt = 0; dt < 8; dt++) {
      bf16x8 vf0 = *(const bf16x8*)(vp[dt]);
      bf16x8 vf1 = *(const bf16x8*)(vp[dt] + 32);
#pragma unroll
      for (int m = 0; m < 2; m++) {
        o[m][dt] = __builtin_amdgcn_mfma_f32_16x16x32_bf16(pf[m][0], vf0, o[m][dt], 0, 0, 0);
        o[m][dt] = __builtin_amdgcn_mfma_f32_16x16x32_bf16(pf[m][1], vf1, o[m][dt], 0, 0, 0);
      }
    }

#pragma unroll
    for (int st = 0; st < 4; st++) kp[st] += (size_t)128 * QKV_N;   // skip 2 tiles
#pragma unroll
    for (int dt = 0; dt < 8; dt++) vp[dt] += 128;
  }

  // ---- one-time l reduce over the 16 column lanes ----
#pragma unroll
  for (int m = 0; m < 2; m++)
#pragma unroll
    for (int r = 0; r < 4; r++)
#pragma unroll
      for (int off = 1; off < 16; off <<= 1)
        lsum[m][r] += __shfl_xor(lsum[m][r], off);

  // ---- combine the two waves' partials via LDS ----
  if (wave == 1) {
#pragma unroll
    for (int m = 0; m < 2; m++)
#pragma unroll
      for (int dt = 0; dt < 8; dt++)
#pragma unroll
        for (int r = 0; r < 4; r++)
          Ex[(m * 16 + quad * 4 + r) * EX_STRIDE + dt * 16 + l16] = o[m][dt][r];
    if (l16 == 0) {
#pragma unroll
      for (int m = 0; m < 2; m++)
#pragma unroll
        for (int r = 0; r < 4; r++)
          Ex[(m * 16 + quad * 4 + r) * EX_STRIDE + 128] = lsum[m][r];
    }
  }
  __syncthreads();
  if (wave == 0) {
#pragma unroll
    for (int m = 0; m < 2; m++) {
      float inv[4];
#pragma unroll
      for (int r = 0; r < 4; r++) {
        float lt = lsum[m][r] + Ex[(m * 16 + quad * 4 + r) * EX_STRIDE + 128];
        inv[r] = 1.0f / lt;
      }
#pragma unroll
      for (int dt = 0; dt < 8; dt++)
#pragma unroll
        for (int r = 0; r < 4; r++) {
          int row = q0 + m * 16 + quad * 4 + r;
          float ov = o[m][dt][r] + Ex[(m * 16 + quad * 4 + r) * EX_STRIDE + dt * 16 + l16];
          attn_out[(size_t)row * HIDDEN + h * HD + dt * 16 + l16] = f2bf(ov * inv[r]);
        }
    }
  }
}

// ---------------- launch ----------------
extern "C" void kernel_launch(void* const* d_in, const int* in_sizes, int n_in,
                              void* d_out, int out_size, void* d_ws, size_t ws_size,
                              hipStream_t stream) {
  const float* x  = (const float*)d_in[0];
  const int* pos  = (const int*)d_in[1];
  const float* Wq = (const float*)d_in[3];
  const float* Wk = (const float*)d_in[4];
  const float* Wv = (const float*)d_in[5];
  const float* Wo = (const float*)d_in[6];
  float* out = (float*)d_out;

  u16* x_bf    = (u16*)d_ws;                                  // 2048*4096
  u16* Wqkv_bf = x_bf + (size_t)SEQ * HIDDEN;                 // 6144*4096
  u16* qkv_bf  = Wqkv_bf + (size_t)QKV_N * HIDDEN;            // 2048*6144
  u16* attn_bf = qkv_bf + (size_t)SEQ * QKV_N;                // 2048*4096
  u16* Wo_bf   = attn_bf + (size_t)SEQ * HIDDEN;              // 4096*4096
  u16* vt_bf   = x_bf;   // reuse x_bf region (dead after gemm1); 1024*2048 fits

  auto cvt = [&](const float* s, u16* d, size_t n) {
    int n8 = (int)(n / 8);
    cvt_f32_bf16<<<(n8 + 255) / 256, 256, 0, stream>>>(s, d, n8);
  };
  cvt(x,  x_bf,    (size_t)SEQ * HIDDEN);
  cvt(Wq, Wqkv_bf,                         (size_t)4096 * 4096);
  cvt(Wk, Wqkv_bf + (size_t)4096 * 4096,   (size_t)1024 * 4096);
  cvt(Wv, Wqkv_bf + (size_t)5120 * 4096,   (size_t)1024 * 4096);
  cvt(Wo, Wo_bf,   (size_t)4096 * 4096);

  dim3 g1(QKV_N / 128, SEQ / 128);
  gemm_bt<0><<<g1, 256, 0, stream>>>(x_bf, Wqkv_bf, qkv_bf, SEQ, QKV_N, HIDDEN);

  int rope_threads = SEQ * 40 * 64;
  rope_kernel<<<rope_threads / 256, 256, 0, stream>>>(qkv_bf, pos);

  dim3 gt(SEQ / 64, 1024 / 64);
  transpose_v<<<gt, 256, 0, stream>>>(qkv_bf, vt_bf);

  attn_kernel<<<2048, 128, 0, stream>>>(qkv_bf, vt_bf, attn_bf);

  dim3 g3(HIDDEN / 128, SEQ / 128);
  gemm_bt<1><<<g3, 256, 0, stream>>>(attn_bf, Wo_bf, out, SEQ, HIDDEN, HIDDEN);
}